// Round 1
// baseline (221.836 us; speedup 1.0000x reference)
//
#include <hip/hip_runtime.h>
#include <hip/hip_bf16.h>
#include <stdint.h>

typedef __attribute__((ext_vector_type(8))) short short8;
typedef __attribute__((ext_vector_type(4))) float floatx4;

#define FEAT_DIM 1536
#define QD 64
#define NROWS 8192
#define TT 513

__device__ __forceinline__ unsigned short f2bf(float x) {
  union { float f; unsigned u; } t; t.f = x;
  unsigned r = t.u + 0x7fffu + ((t.u >> 16) & 1u);
  return (unsigned short)(r >> 16);
}
__device__ __forceinline__ float bf2f(unsigned short u) {
  union { float f; unsigned u; } t; t.u = ((unsigned)u) << 16;
  return t.f;
}

// K0: proj [1536][64] fp32 -> pbt [64][1536] bf16 (k-contiguous rows for B-frags)
__global__ __launch_bounds__(256) void k_projt(const float* __restrict__ proj,
                                               unsigned short* __restrict__ pbt) {
  int k = blockIdx.x * 256 + threadIdx.x;  // 0..1535
  int n = blockIdx.y;                      // 0..63
  pbt[n * FEAT_DIM + k] = f2bf(proj[k * QD + n]);
}

// K1: sf = win @ proj via MFMA bf16. Block = 16 rows, 4 waves split K (384 each).
__global__ __launch_bounds__(256) void k_sf(const float* __restrict__ feat,
                                            const unsigned short* __restrict__ pbt,
                                            unsigned short* __restrict__ sfb,
                                            float* __restrict__ sq) {
  const int tid = threadIdx.x;
  const int wave = tid >> 6, lane = tid & 63;
  const int q = lane >> 4, n = lane & 15;
  const int rbase = blockIdx.x * 16;
  const int row = rbase + n;
  const int b = row >> 9, ti = row & 511;
  const float* fb = feat + (size_t)(b * TT + ti) * FEAT_DIM;
  const short8* pb = (const short8*)pbt;

  floatx4 acc0 = {0,0,0,0}, acc1 = {0,0,0,0}, acc2 = {0,0,0,0}, acc3 = {0,0,0,0};
  const int kw = wave * 384;

  for (int ks = 0; ks < 12; ++ks) {
    int koff = kw + ks * 32 + q * 8;
    floatx4 f0 = *(const floatx4*)(fb + koff);
    floatx4 f1 = *(const floatx4*)(fb + koff + 4);
    floatx4 g0 = *(const floatx4*)(fb + FEAT_DIM + koff);
    floatx4 g1 = *(const floatx4*)(fb + FEAT_DIM + koff + 4);
    union { unsigned short u[8]; short8 v; } A;
#pragma unroll
    for (int j = 0; j < 4; ++j) A.u[j] = f2bf(0.5f * (f0[j] + g0[j]));
#pragma unroll
    for (int j = 0; j < 4; ++j) A.u[4 + j] = f2bf(0.5f * (f1[j] + g1[j]));
    int bi = n * 192 + (kw >> 3) + ks * 4 + q;
    short8 B0 = pb[bi];
    short8 B1 = pb[bi + 16 * 192];
    short8 B2 = pb[bi + 32 * 192];
    short8 B3 = pb[bi + 48 * 192];
    acc0 = __builtin_amdgcn_mfma_f32_16x16x32_bf16(A.v, B0, acc0, 0, 0, 0);
    acc1 = __builtin_amdgcn_mfma_f32_16x16x32_bf16(A.v, B1, acc1, 0, 0, 0);
    acc2 = __builtin_amdgcn_mfma_f32_16x16x32_bf16(A.v, B2, acc2, 0, 0, 0);
    acc3 = __builtin_amdgcn_mfma_f32_16x16x32_bf16(A.v, B3, acc3, 0, 0, 0);
  }

  __shared__ float part[4][16][64];
#pragma unroll
  for (int r = 0; r < 4; ++r) {
    part[wave][q * 4 + r][0 * 16 + n] = acc0[r];
    part[wave][q * 4 + r][1 * 16 + n] = acc1[r];
    part[wave][q * 4 + r][2 * 16 + n] = acc2[r];
    part[wave][q * 4 + r][3 * 16 + n] = acc3[r];
  }
  __syncthreads();
  {
    const int r = tid >> 4;          // 0..15
    const int c0 = (tid & 15) * 4;   // 0..60
    float sqp = 0.0f;
    unsigned short ub[4];
#pragma unroll
    for (int j = 0; j < 4; ++j) {
      float v = part[0][r][c0 + j] + part[1][r][c0 + j] +
                part[2][r][c0 + j] + part[3][r][c0 + j];
      ub[j] = f2bf(v);
      float bv = bf2f(ub[j]);
      sqp += bv * bv;
    }
    union { unsigned short u[4]; uint2 d; } P;
    P.u[0] = ub[0]; P.u[1] = ub[1]; P.u[2] = ub[2]; P.u[3] = ub[3];
    *(uint2*)(sfb + (size_t)(rbase + r) * QD + c0) = P.d;
#pragma unroll
    for (int off = 1; off < 16; off <<= 1) sqp += __shfl_xor(sqp, off, 64);
    if ((tid & 15) == 0) sq[rbase + r] = sqp;
  }
}

// K2: fused pairwise-dot (MFMA) + per-row branchless top-16 + merge + sqrt-sum.
// Block = one 16-row i-tile; wave w covers j in [w*2048, (w+1)*2048).
// C orientation: D[m=j][n=i]; lane owns ONE i-list (n = lane&15), 4 j's per tile.
__global__ __launch_bounds__(256) void k_knn(const unsigned short* __restrict__ sfb,
                                             const float* __restrict__ sq,
                                             float* __restrict__ intrew,
                                             float* __restrict__ accum) {
  const int tid = threadIdx.x;
  const int wave = tid >> 6, lane = tid & 63;
  const int q = lane >> 4, n = lane & 15;
  const int ib = blockIdx.x * 16;
  const short8* sfv = (const short8*)sfb;

  // B-frag (i-tile rows), fixed for whole kernel
  short8 b0 = sfv[(ib + n) * 8 + q];
  short8 b1 = sfv[(ib + n) * 8 + 4 + q];

  float lst[16];
#pragma unroll
  for (int k = 0; k < 16; ++k) lst[k] = 3.0e38f;

  const int j0 = wave * 2048;
  short8 A0 = sfv[(j0 + n) * 8 + q];
  short8 A1 = sfv[(j0 + n) * 8 + 4 + q];
  floatx4 s4 = *(const floatx4*)(sq + j0 + q * 4);

  for (int jt = 0; jt < 2048; jt += 16) {
    const int jb = j0 + jt;
    const int jn = (jb + 16) & (NROWS - 1);     // wrapped prefetch (harmless tail)
    short8 nA0 = sfv[(jn + n) * 8 + q];
    short8 nA1 = sfv[(jn + n) * 8 + 4 + q];
    floatx4 ns4 = *(const floatx4*)(sq + jn + q * 4);

    floatx4 acc = {0, 0, 0, 0};
    acc = __builtin_amdgcn_mfma_f32_16x16x32_bf16(A0, b0, acc, 0, 0, 0);
    acc = __builtin_amdgcn_mfma_f32_16x16x32_bf16(A1, b1, acc, 0, 0, 0);

#pragma unroll
    for (int r = 0; r < 4; ++r) {
      float c = fmaf(-2.0f, acc[r], s4[r]);   // key = sq_j - 2*dot (monotone in dist)
      // branchless sorted-ascending insert, keep 16 smallest
#pragma unroll
      for (int k = 15; k >= 1; --k) lst[k] = fminf(lst[k], fmaxf(lst[k - 1], c));
      lst[0] = fminf(lst[0], c);
    }
    A0 = nA0; A1 = nA1; s4 = ns4;
  }

  __shared__ float lists[16][16][17];  // [i-row][sublist][16 sorted + 1 pad]
  const int sl = wave * 4 + q;
#pragma unroll
  for (int k = 0; k < 16; ++k) lists[n][sl][k] = lst[k];
  __syncthreads();

  // Tournament merge: wave w handles rows w*4..w*4+3; 16 lanes per row = 16 sublists.
  const int sub = lane & 15;
  const int rr = wave * 4 + (lane >> 4);
  const float sqr = sq[ib + rr];
  int p = 0;
  float h = lists[rr][sub][0];
  float sum = 0.0f;
#pragma unroll 1
  for (int it = 0; it < 16; ++it) {
    float v = h; int idx = sub;
#pragma unroll
    for (int off = 1; off < 16; off <<= 1) {
      float v2 = __shfl_xor(v, off, 64);
      int i2 = __shfl_xor(idx, off, 64);
      if (v2 < v || (v2 == v && i2 < idx)) { v = v2; idx = i2; }
    }
    sum += sqrtf(fmaxf(sqr + v, 1e-12f));
    if (idx == sub) { ++p; h = lists[rr][sub][p]; }
  }
  if (sub == 0) {
    float ir = sum * (1.0f / 16.0f);
    intrew[ib + rr] = ir;
    atomicAdd(accum, ir);
  }
}

// K3: StreamNorm + add reward
__global__ __launch_bounds__(256) void k_final(const float* __restrict__ reward,
                                               const float* __restrict__ intrew,
                                               const float* __restrict__ accum,
                                               float* __restrict__ out) {
  int i = blockIdx.x * 256 + threadIdx.x;   // 0..8191
  float mean = accum[0] * (1.0f / 8192.0f);
  float mag = 0.99f + 0.01f * mean;
  int b = i >> 9, ti = i & 511;
  out[i] = reward[b * TT + ti] + intrew[i] / (mag + 1e-8f);
}

extern "C" void kernel_launch(void* const* d_in, const int* in_sizes, int n_in,
                              void* d_out, int out_size, void* d_ws, size_t ws_size,
                              hipStream_t stream) {
  const float* feat   = (const float*)d_in[0];
  const float* reward = (const float*)d_in[1];
  const float* proj   = (const float*)d_in[2];
  float* out = (float*)d_out;

  char* ws = (char*)d_ws;
  unsigned short* sfb    = (unsigned short*)ws;                       // 1 MB: sf bf16 [8192][64]
  float* sq              = (float*)(ws + (1 << 20));                  // 32 KB
  float* intrew          = (float*)(ws + (1 << 20) + 32768);          // 32 KB
  float* accum           = (float*)(ws + (1 << 20) + 65536);          // 4 B
  unsigned short* pbt    = (unsigned short*)(ws + (1 << 20) + 65536 + 256);  // 192 KB

  hipMemsetAsync(accum, 0, sizeof(float), stream);
  k_projt<<<dim3(6, 64), 256, 0, stream>>>(proj, pbt);
  k_sf<<<512, 256, 0, stream>>>(feat, pbt, sfb, sq);
  k_knn<<<512, 256, 0, stream>>>(sfb, sq, intrew, accum);
  k_final<<<32, 256, 0, stream>>>(reward, intrew, accum, out);
}

// Round 2
// 220.975 us; speedup vs baseline: 1.0039x; 1.0039x over previous
//
#include <hip/hip_runtime.h>
#include <hip/hip_bf16.h>
#include <stdint.h>

typedef __attribute__((ext_vector_type(8))) short short8;
typedef __attribute__((ext_vector_type(4))) float floatx4;

#define FEAT_DIM 1536
#define QD 64
#define NROWS 8192
#define TT 513

__device__ __forceinline__ unsigned short f2bf(float x) {
  union { float f; unsigned u; } t; t.f = x;
  unsigned r = t.u + 0x7fffu + ((t.u >> 16) & 1u);
  return (unsigned short)(r >> 16);
}
__device__ __forceinline__ float bf2f(unsigned short u) {
  union { float f; unsigned u; } t; t.u = ((unsigned)u) << 16;
  return t.f;
}

// K0: proj [1536][64] fp32 -> pbt [64][1536] bf16 (k-contiguous rows for B-frags)
__global__ __launch_bounds__(256) void k_projt(const float* __restrict__ proj,
                                               unsigned short* __restrict__ pbt) {
  int k = blockIdx.x * 256 + threadIdx.x;  // 0..1535
  int n = blockIdx.y;                      // 0..63
  pbt[n * FEAT_DIM + k] = f2bf(proj[k * QD + n]);
}

// K1: sf = win @ proj via MFMA bf16. Block = 16 rows, 4 waves split K (384 each).
__global__ __launch_bounds__(256) void k_sf(const float* __restrict__ feat,
                                            const unsigned short* __restrict__ pbt,
                                            unsigned short* __restrict__ sfb,
                                            float* __restrict__ sq) {
  const int tid = threadIdx.x;
  const int wave = tid >> 6, lane = tid & 63;
  const int q = lane >> 4, n = lane & 15;
  const int rbase = blockIdx.x * 16;
  const int row = rbase + n;
  const int b = row >> 9, ti = row & 511;
  const float* fb = feat + (size_t)(b * TT + ti) * FEAT_DIM;
  const short8* pb = (const short8*)pbt;

  floatx4 acc0 = {0,0,0,0}, acc1 = {0,0,0,0}, acc2 = {0,0,0,0}, acc3 = {0,0,0,0};
  const int kw = wave * 384;

  for (int ks = 0; ks < 12; ++ks) {
    int koff = kw + ks * 32 + q * 8;
    floatx4 f0 = *(const floatx4*)(fb + koff);
    floatx4 f1 = *(const floatx4*)(fb + koff + 4);
    floatx4 g0 = *(const floatx4*)(fb + FEAT_DIM + koff);
    floatx4 g1 = *(const floatx4*)(fb + FEAT_DIM + koff + 4);
    union { unsigned short u[8]; short8 v; } A;
#pragma unroll
    for (int j = 0; j < 4; ++j) A.u[j] = f2bf(0.5f * (f0[j] + g0[j]));
#pragma unroll
    for (int j = 0; j < 4; ++j) A.u[4 + j] = f2bf(0.5f * (f1[j] + g1[j]));
    int bi = n * 192 + (kw >> 3) + ks * 4 + q;
    short8 B0 = pb[bi];
    short8 B1 = pb[bi + 16 * 192];
    short8 B2 = pb[bi + 32 * 192];
    short8 B3 = pb[bi + 48 * 192];
    acc0 = __builtin_amdgcn_mfma_f32_16x16x32_bf16(A.v, B0, acc0, 0, 0, 0);
    acc1 = __builtin_amdgcn_mfma_f32_16x16x32_bf16(A.v, B1, acc1, 0, 0, 0);
    acc2 = __builtin_amdgcn_mfma_f32_16x16x32_bf16(A.v, B2, acc2, 0, 0, 0);
    acc3 = __builtin_amdgcn_mfma_f32_16x16x32_bf16(A.v, B3, acc3, 0, 0, 0);
  }

  __shared__ float part[4][16][64];
#pragma unroll
  for (int r = 0; r < 4; ++r) {
    part[wave][q * 4 + r][0 * 16 + n] = acc0[r];
    part[wave][q * 4 + r][1 * 16 + n] = acc1[r];
    part[wave][q * 4 + r][2 * 16 + n] = acc2[r];
    part[wave][q * 4 + r][3 * 16 + n] = acc3[r];
  }
  __syncthreads();
  {
    const int r = tid >> 4;          // 0..15
    const int c0 = (tid & 15) * 4;   // 0..60
    float sqp = 0.0f;
    unsigned short ub[4];
#pragma unroll
    for (int j = 0; j < 4; ++j) {
      float v = part[0][r][c0 + j] + part[1][r][c0 + j] +
                part[2][r][c0 + j] + part[3][r][c0 + j];
      ub[j] = f2bf(v);
      float bv = bf2f(ub[j]);
      sqp += bv * bv;
    }
    union { unsigned short u[4]; uint2 d; } P;
    P.u[0] = ub[0]; P.u[1] = ub[1]; P.u[2] = ub[2]; P.u[3] = ub[3];
    *(uint2*)(sfb + (size_t)(rbase + r) * QD + c0) = P.d;
#pragma unroll
    for (int off = 1; off < 16; off <<= 1) sqp += __shfl_xor(sqp, off, 64);
    if ((tid & 15) == 0) sq[rbase + r] = sqp;
  }
}

// K2: fused pairwise-dot (MFMA) + per-row branchless top-16 via med3 insert net.
// Block = (i-tile of 16 rows) x (j-split of 2048). Wave covers 512 j's.
// C orientation: D[m=j][n=i]; lane owns ONE i-list (n = lane&15), 4 j's per tile.
// Emits per-(block,row) sorted top-16 to tops[row][4 splits][16].
__global__ __launch_bounds__(256) void k_knn(const unsigned short* __restrict__ sfb,
                                             const float* __restrict__ sq,
                                             float* __restrict__ tops) {
  const int tid = threadIdx.x;
  const int wave = tid >> 6, lane = tid & 63;
  const int q = lane >> 4, n = lane & 15;
  const int ib = (blockIdx.x >> 2) * 16;
  const int js = blockIdx.x & 3;
  const short8* sfv = (const short8*)sfb;

  // B-frag (i-tile rows), fixed for whole kernel
  short8 b0 = sfv[(ib + n) * 8 + q];
  short8 b1 = sfv[(ib + n) * 8 + 4 + q];

  float lst[16];
#pragma unroll
  for (int k = 0; k < 16; ++k) lst[k] = 3.0e38f;

  const int j0 = js * 2048 + wave * 512;
  short8 A0 = sfv[(j0 + n) * 8 + q];
  short8 A1 = sfv[(j0 + n) * 8 + 4 + q];
  floatx4 s4 = *(const floatx4*)(sq + j0 + q * 4);

  for (int jt = 0; jt < 512; jt += 16) {
    const int jn = (j0 + jt + 16) & (NROWS - 1);     // wrapped prefetch (harmless tail)
    short8 nA0 = sfv[(jn + n) * 8 + q];
    short8 nA1 = sfv[(jn + n) * 8 + 4 + q];
    floatx4 ns4 = *(const floatx4*)(sq + jn + q * 4);

    floatx4 acc = {0, 0, 0, 0};
    acc = __builtin_amdgcn_mfma_f32_16x16x32_bf16(A0, b0, acc, 0, 0, 0);
    acc = __builtin_amdgcn_mfma_f32_16x16x32_bf16(A1, b1, acc, 0, 0, 0);

#pragma unroll
    for (int r = 0; r < 4; ++r) {
      float c = fmaf(-2.0f, acc[r], s4[r]);   // key = sq_j - 2*dot (monotone in dist)
      // sorted-ascending insert: since lst[k-1] <= lst[k],
      // min(lst[k], max(lst[k-1], c)) == med3(lst[k], lst[k-1], c)  -> 16 ops
#pragma unroll
      for (int k = 15; k >= 1; --k)
        lst[k] = __builtin_amdgcn_fmed3f(lst[k], lst[k - 1], c);
      lst[0] = fminf(lst[0], c);
    }
    A0 = nA0; A1 = nA1; s4 = ns4;
  }

  // [sublist][row][k]: bank = (16q + 17n + k) mod 32 -> worst 2-way (free)
  __shared__ float lists[16][16][17];
  const int sl = wave * 4 + q;
#pragma unroll
  for (int k = 0; k < 16; ++k) lists[sl][n][k] = lst[k];
  __syncthreads();

  // Tournament merge: wave w handles rows w*4..w*4+3; 16 lanes per row = 16 sublists.
  const int sub = lane & 15;
  const int rr = wave * 4 + (lane >> 4);
  int p = 0;
  float h = lists[sub][rr][0];
  float* trow = tops + ((size_t)(ib + rr) * 4 + js) * 16;
#pragma unroll 1
  for (int it = 0; it < 16; ++it) {
    float v = h; int idx = sub;
#pragma unroll
    for (int off = 1; off < 16; off <<= 1) {
      float v2 = __shfl_xor(v, off, 64);
      int i2 = __shfl_xor(idx, off, 64);
      if (v2 < v || (v2 == v && i2 < idx)) { v = v2; idx = i2; }
    }
    if (sub == 0) trow[it] = v;
    if (idx == sub) { ++p; h = lists[sub][rr][p]; }
  }
}

// K2b: per row, merge 4 partial top-16s (64 candidates) -> top-16, sqrt-sum, mean.
__global__ __launch_bounds__(256) void k_merge(const float* __restrict__ tops,
                                               const float* __restrict__ sq,
                                               float* __restrict__ intrew,
                                               float* __restrict__ accum) {
  const int tid = threadIdx.x;
  const int wave = tid >> 6, lane = tid & 63;
  const int row = blockIdx.x * 4 + wave;
  float v = tops[(size_t)row * 64 + lane];
  const float sqr = sq[row];
  float sum = 0.0f;
#pragma unroll 1
  for (int it = 0; it < 16; ++it) {
    float m = v; int idx = lane;
#pragma unroll
    for (int off = 1; off < 64; off <<= 1) {
      float v2 = __shfl_xor(m, off, 64);
      int i2 = __shfl_xor(idx, off, 64);
      if (v2 < m || (v2 == m && i2 < idx)) { m = v2; idx = i2; }
    }
    sum += sqrtf(fmaxf(sqr + m, 1e-12f));
    if (lane == idx) v = 3.0e38f;   // remove exactly one winner
  }
  __shared__ float bsum;
  if (tid == 0) bsum = 0.0f;
  __syncthreads();
  if (lane == 0) {
    float ir = sum * (1.0f / 16.0f);
    intrew[row] = ir;
    atomicAdd(&bsum, ir);
  }
  __syncthreads();
  if (tid == 0) atomicAdd(accum, bsum);
}

// K3: StreamNorm + add reward
__global__ __launch_bounds__(256) void k_final(const float* __restrict__ reward,
                                               const float* __restrict__ intrew,
                                               const float* __restrict__ accum,
                                               float* __restrict__ out) {
  int i = blockIdx.x * 256 + threadIdx.x;   // 0..8191
  float mean = accum[0] * (1.0f / 8192.0f);
  float mag = 0.99f + 0.01f * mean;
  int b = i >> 9, ti = i & 511;
  out[i] = reward[b * TT + ti] + intrew[i] / (mag + 1e-8f);
}

extern "C" void kernel_launch(void* const* d_in, const int* in_sizes, int n_in,
                              void* d_out, int out_size, void* d_ws, size_t ws_size,
                              hipStream_t stream) {
  const float* feat   = (const float*)d_in[0];
  const float* reward = (const float*)d_in[1];
  const float* proj   = (const float*)d_in[2];
  float* out = (float*)d_out;

  char* ws = (char*)d_ws;
  unsigned short* sfb = (unsigned short*)ws;                   // 1 MB: sf bf16 [8192][64]
  float* sq           = (float*)(ws + 0x100000);               // 32 KB
  float* intrew       = (float*)(ws + 0x110000);               // 32 KB
  float* accum        = (float*)(ws + 0x120000);               // 4 B
  unsigned short* pbt = (unsigned short*)(ws + 0x130000);      // 192 KB
  float* tops         = (float*)(ws + 0x160000);               // 2 MB: [8192][4][16]

  hipMemsetAsync(accum, 0, sizeof(float), stream);
  k_projt<<<dim3(6, 64), 256, 0, stream>>>(proj, pbt);
  k_sf<<<512, 256, 0, stream>>>(feat, pbt, sfb, sq);
  k_knn<<<2048, 256, 0, stream>>>(sfb, sq, tops);
  k_merge<<<2048, 256, 0, stream>>>(tops, sq, intrew, accum);
  k_final<<<32, 256, 0, stream>>>(reward, intrew, accum, out);
}

// Round 3
// 204.947 us; speedup vs baseline: 1.0824x; 1.0782x over previous
//
#include <hip/hip_runtime.h>
#include <hip/hip_bf16.h>
#include <stdint.h>

typedef __attribute__((ext_vector_type(8))) short short8;
typedef __attribute__((ext_vector_type(4))) float floatx4;

#define FEAT_DIM 1536
#define QD 64
#define NROWS 8192
#define TT 513

__device__ __forceinline__ unsigned short f2bf(float x) {
  union { float f; unsigned u; } t; t.f = x;
  unsigned r = t.u + 0x7fffu + ((t.u >> 16) & 1u);
  return (unsigned short)(r >> 16);
}
__device__ __forceinline__ float bf2f(unsigned short u) {
  union { float f; unsigned u; } t; t.u = ((unsigned)u) << 16;
  return t.f;
}

// K0: proj [1536][64] fp32 -> pbt [64][1536] bf16 (k-contiguous rows for B-frags)
__global__ __launch_bounds__(256) void k_projt(const float* __restrict__ proj,
                                               unsigned short* __restrict__ pbt) {
  int k = blockIdx.x * 256 + threadIdx.x;  // 0..1535
  int n = blockIdx.y;                      // 0..63
  pbt[n * FEAT_DIM + k] = f2bf(proj[k * QD + n]);
}

// K1: sf = win @ proj via MFMA bf16. Block = 16 rows, 8 waves split K (192 each).
// Software-pipelined feat loads (sched_barrier pins prefetch before compute).
__global__ __launch_bounds__(512) void k_sf(const float* __restrict__ feat,
                                            const unsigned short* __restrict__ pbt,
                                            unsigned short* __restrict__ sfb,
                                            float* __restrict__ sq) {
  const int tid = threadIdx.x;
  const int wave = tid >> 6, lane = tid & 63;
  const int q = lane >> 4, n = lane & 15;
  const int rbase = blockIdx.x * 16;
  const int row = rbase + n;
  const int b = row >> 9, ti = row & 511;
  const float* fb = feat + (size_t)(b * TT + ti) * FEAT_DIM;
  const short8* pb = (const short8*)pbt;
  const int kw = wave * 192;

  floatx4 acc0 = {0,0,0,0}, acc1 = {0,0,0,0}, acc2 = {0,0,0,0}, acc3 = {0,0,0,0};

  int koff = kw + q * 8;
  floatx4 f0 = *(const floatx4*)(fb + koff);
  floatx4 f1 = *(const floatx4*)(fb + koff + 4);
  floatx4 g0 = *(const floatx4*)(fb + FEAT_DIM + koff);
  floatx4 g1 = *(const floatx4*)(fb + FEAT_DIM + koff + 4);
  const int bi0 = n * 192 + wave * 24 + q;

  for (int ks = 0; ks < 6; ++ks) {
    floatx4 nf0, nf1, ng0, ng1;
    if (ks < 5) {
      int ko = kw + (ks + 1) * 32 + q * 8;
      nf0 = *(const floatx4*)(fb + ko);
      nf1 = *(const floatx4*)(fb + ko + 4);
      ng0 = *(const floatx4*)(fb + FEAT_DIM + ko);
      ng1 = *(const floatx4*)(fb + FEAT_DIM + ko + 4);
    }
    int bi = bi0 + ks * 4;
    short8 B0 = pb[bi];
    short8 B1 = pb[bi + 16 * 192];
    short8 B2 = pb[bi + 32 * 192];
    short8 B3 = pb[bi + 48 * 192];
    __builtin_amdgcn_sched_barrier(0);   // keep prefetch issue ahead of compute
    union { unsigned short u[8]; short8 v; } A;
#pragma unroll
    for (int j = 0; j < 4; ++j) A.u[j] = f2bf(0.5f * (f0[j] + g0[j]));
#pragma unroll
    for (int j = 0; j < 4; ++j) A.u[4 + j] = f2bf(0.5f * (f1[j] + g1[j]));
    acc0 = __builtin_amdgcn_mfma_f32_16x16x32_bf16(A.v, B0, acc0, 0, 0, 0);
    acc1 = __builtin_amdgcn_mfma_f32_16x16x32_bf16(A.v, B1, acc1, 0, 0, 0);
    acc2 = __builtin_amdgcn_mfma_f32_16x16x32_bf16(A.v, B2, acc2, 0, 0, 0);
    acc3 = __builtin_amdgcn_mfma_f32_16x16x32_bf16(A.v, B3, acc3, 0, 0, 0);
    if (ks < 5) { f0 = nf0; f1 = nf1; g0 = ng0; g1 = ng1; }
  }

  __shared__ float part[8][16][64];
#pragma unroll
  for (int r = 0; r < 4; ++r) {
    part[wave][q * 4 + r][0 * 16 + n] = acc0[r];
    part[wave][q * 4 + r][1 * 16 + n] = acc1[r];
    part[wave][q * 4 + r][2 * 16 + n] = acc2[r];
    part[wave][q * 4 + r][3 * 16 + n] = acc3[r];
  }
  __syncthreads();
  {
    const int r = tid >> 5;           // 0..15
    const int c0 = (tid & 31) * 2;    // 0..62
    float sqp = 0.0f;
    unsigned short ub[2];
#pragma unroll
    for (int j = 0; j < 2; ++j) {
      float v = 0.0f;
#pragma unroll
      for (int w = 0; w < 8; ++w) v += part[w][r][c0 + j];
      ub[j] = f2bf(v);
      float bv = bf2f(ub[j]);
      sqp += bv * bv;
    }
    union { unsigned short u[2]; unsigned d; } P;
    P.u[0] = ub[0]; P.u[1] = ub[1];
    *(unsigned*)(sfb + (size_t)(rbase + r) * QD + c0) = P.d;
#pragma unroll
    for (int off = 1; off < 32; off <<= 1) sqp += __shfl_xor(sqp, off, 64);
    if ((tid & 31) == 0) sq[rbase + r] = sqp;
  }
}

// K2: fused pairwise-dot (MFMA) + per-row branchless top-16 via med3 insert net.
// Block = (i-tile of 32 rows) x (j-split of 2048). Wave covers 512 j's.
// Lane owns TWO i-lists (rows ib+n and ib+16+n); 4 j's per list per tile.
__global__ __launch_bounds__(256) void k_knn(const unsigned short* __restrict__ sfb,
                                             const float* __restrict__ sq,
                                             float* __restrict__ tops) {
  const int tid = threadIdx.x;
  const int wave = tid >> 6, lane = tid & 63;
  const int q = lane >> 4, n = lane & 15;
  const int ib = (blockIdx.x >> 2) * 32;
  const int js = blockIdx.x & 3;
  const short8* sfv = (const short8*)sfb;

  // B-frags: rows ib+n (b0,b1) and ib+16+n (b2,b3)
  short8 b0 = sfv[(ib + n) * 8 + q];
  short8 b1 = sfv[(ib + n) * 8 + 4 + q];
  short8 b2 = sfv[(ib + 16 + n) * 8 + q];
  short8 b3 = sfv[(ib + 16 + n) * 8 + 4 + q];

  float lst0[16], lst1[16];
#pragma unroll
  for (int k = 0; k < 16; ++k) { lst0[k] = 3.0e38f; lst1[k] = 3.0e38f; }

  const int j0 = js * 2048 + wave * 512;
  short8 A0 = sfv[(j0 + n) * 8 + q];
  short8 A1 = sfv[(j0 + n) * 8 + 4 + q];
  floatx4 s4 = *(const floatx4*)(sq + j0 + q * 4);

  for (int jt = 0; jt < 512; jt += 16) {
    const int jn = (j0 + jt + 16) & (NROWS - 1);   // wrapped prefetch (harmless tail)
    short8 nA0 = sfv[(jn + n) * 8 + q];
    short8 nA1 = sfv[(jn + n) * 8 + 4 + q];
    floatx4 ns4 = *(const floatx4*)(sq + jn + q * 4);
    __builtin_amdgcn_sched_barrier(0);   // pin prefetch issue before compute

    floatx4 acc0 = {0, 0, 0, 0};
    acc0 = __builtin_amdgcn_mfma_f32_16x16x32_bf16(A0, b0, acc0, 0, 0, 0);
    acc0 = __builtin_amdgcn_mfma_f32_16x16x32_bf16(A1, b1, acc0, 0, 0, 0);
    floatx4 acc1 = {0, 0, 0, 0};
    acc1 = __builtin_amdgcn_mfma_f32_16x16x32_bf16(A0, b2, acc1, 0, 0, 0);
    acc1 = __builtin_amdgcn_mfma_f32_16x16x32_bf16(A1, b3, acc1, 0, 0, 0);

#pragma unroll
    for (int r = 0; r < 4; ++r) {
      float c = fmaf(-2.0f, acc0[r], s4[r]);   // key = sq_j - 2*dot
#pragma unroll
      for (int k = 15; k >= 1; --k)
        lst0[k] = __builtin_amdgcn_fmed3f(lst0[k], lst0[k - 1], c);
      lst0[0] = fminf(lst0[0], c);
    }
#pragma unroll
    for (int r = 0; r < 4; ++r) {
      float c = fmaf(-2.0f, acc1[r], s4[r]);
#pragma unroll
      for (int k = 15; k >= 1; --k)
        lst1[k] = __builtin_amdgcn_fmed3f(lst1[k], lst1[k - 1], c);
      lst1[0] = fminf(lst1[0], c);
    }
    A0 = nA0; A1 = nA1; s4 = ns4;
  }

  // [sublist][row][k], row-stride 17, sublist-stride 561 (=17 mod 32): conflict-light
  __shared__ float lists[16][33][17];
  const int sl = wave * 4 + q;
#pragma unroll
  for (int k = 0; k < 16; ++k) {
    lists[sl][n][k] = lst0[k];
    lists[sl][n + 16][k] = lst1[k];
  }
  __syncthreads();

  // Tournament merge: wave w rows w*8..w*8+7, two passes of 4 rows (16 lanes/row).
  const int sub = lane & 15;
#pragma unroll 1
  for (int pass = 0; pass < 2; ++pass) {
    const int rr = wave * 8 + (lane >> 4) + 4 * pass;
    int p = 0;
    float h = lists[sub][rr][0];
    float* trow = tops + ((size_t)(ib + rr) * 4 + js) * 16;
#pragma unroll 1
    for (int it = 0; it < 16; ++it) {
      float v = h; int idx = sub;
#pragma unroll
      for (int off = 1; off < 16; off <<= 1) {
        float v2 = __shfl_xor(v, off, 64);
        int i2 = __shfl_xor(idx, off, 64);
        if (v2 < v || (v2 == v && i2 < idx)) { v = v2; idx = i2; }
      }
      if (sub == 0) trow[it] = v;
      if (idx == sub) { ++p; h = lists[sub][rr][p]; }
    }
  }
}

// K2b: per row, merge 4 partial top-16s (64 candidates) -> top-16, sqrt-sum, mean.
__global__ __launch_bounds__(256) void k_merge(const float* __restrict__ tops,
                                               const float* __restrict__ sq,
                                               float* __restrict__ intrew,
                                               float* __restrict__ accum) {
  const int tid = threadIdx.x;
  const int wave = tid >> 6, lane = tid & 63;
  const int row = blockIdx.x * 4 + wave;
  float v = tops[(size_t)row * 64 + lane];
  const float sqr = sq[row];
  float sum = 0.0f;
#pragma unroll 1
  for (int it = 0; it < 16; ++it) {
    float m = v; int idx = lane;
#pragma unroll
    for (int off = 1; off < 64; off <<= 1) {
      float v2 = __shfl_xor(m, off, 64);
      int i2 = __shfl_xor(idx, off, 64);
      if (v2 < m || (v2 == m && i2 < idx)) { m = v2; idx = i2; }
    }
    sum += sqrtf(fmaxf(sqr + m, 1e-12f));
    if (lane == idx) v = 3.0e38f;   // remove exactly one winner
  }
  __shared__ float bsum;
  if (tid == 0) bsum = 0.0f;
  __syncthreads();
  if (lane == 0) {
    float ir = sum * (1.0f / 16.0f);
    intrew[row] = ir;
    atomicAdd(&bsum, ir);
  }
  __syncthreads();
  if (tid == 0) atomicAdd(accum, bsum);
}

// K3: StreamNorm + add reward
__global__ __launch_bounds__(256) void k_final(const float* __restrict__ reward,
                                               const float* __restrict__ intrew,
                                               const float* __restrict__ accum,
                                               float* __restrict__ out) {
  int i = blockIdx.x * 256 + threadIdx.x;   // 0..8191
  float mean = accum[0] * (1.0f / 8192.0f);
  float mag = 0.99f + 0.01f * mean;
  int b = i >> 9, ti = i & 511;
  out[i] = reward[b * TT + ti] + intrew[i] / (mag + 1e-8f);
}

extern "C" void kernel_launch(void* const* d_in, const int* in_sizes, int n_in,
                              void* d_out, int out_size, void* d_ws, size_t ws_size,
                              hipStream_t stream) {
  const float* feat   = (const float*)d_in[0];
  const float* reward = (const float*)d_in[1];
  const float* proj   = (const float*)d_in[2];
  float* out = (float*)d_out;

  char* ws = (char*)d_ws;
  unsigned short* sfb = (unsigned short*)ws;                   // 1 MB: sf bf16 [8192][64]
  float* sq           = (float*)(ws + 0x100000);               // 32 KB
  float* intrew       = (float*)(ws + 0x110000);               // 32 KB
  float* accum        = (float*)(ws + 0x120000);               // 4 B
  unsigned short* pbt = (unsigned short*)(ws + 0x130000);      // 192 KB
  float* tops         = (float*)(ws + 0x160000);               // 2 MB: [8192][4][16]

  hipMemsetAsync(accum, 0, sizeof(float), stream);
  k_projt<<<dim3(6, 64), 256, 0, stream>>>(proj, pbt);
  k_sf<<<512, 512, 0, stream>>>(feat, pbt, sfb, sq);
  k_knn<<<1024, 256, 0, stream>>>(sfb, sq, tops);
  k_merge<<<2048, 256, 0, stream>>>(tops, sq, intrew, accum);
  k_final<<<32, 256, 0, stream>>>(reward, intrew, accum, out);
}